// Round 1
// baseline (464.957 us; speedup 1.0000x reference)
//
#include <hip/hip_runtime.h>
#include <hip/hip_bf16.h>

// ODELSTMCell: B=16384, I=256, H=256, OH=64, 8 fixed dopri5 steps.
// Kernel 1: LSTM gates GEMM (MFMA bf16, no LDS) + fused epilogue.
//   writes c -> d_out[B*H .. 2*B*H), h (=y0) -> d_out[0 .. B*H)
// Kernel 2: dopri5 ODE integrator, 16 samples/block, MFMA evals,
//   state in swizzled LDS f32, weights as register B-frags.

#define B_N 16384
#define H_N 256

typedef __attribute__((ext_vector_type(8))) short short8;   // 8 x bf16 (4 VGPR)
typedef __attribute__((ext_vector_type(4))) short short4v;  // 4 x bf16
typedef __attribute__((ext_vector_type(4))) float f32x4;

__device__ __forceinline__ unsigned short f2bf(float x) {
  unsigned u = __float_as_uint(x);
  u += 0x7fffu + ((u >> 16) & 1u);            // RNE
  return (unsigned short)(u >> 16);
}

__device__ __forceinline__ short8 pack8(const float* p) {
  const f32x4 a = *(const f32x4*)p;
  const f32x4 b = *(const f32x4*)(p + 4);
  short8 r;
  r[0] = (short)f2bf(a[0]); r[1] = (short)f2bf(a[1]);
  r[2] = (short)f2bf(a[2]); r[3] = (short)f2bf(a[3]);
  r[4] = (short)f2bf(b[0]); r[5] = (short)f2bf(b[1]);
  r[6] = (short)f2bf(b[2]); r[7] = (short)f2bf(b[3]);
  return r;
}

__device__ __forceinline__ float fast_sigmoid(float x) {
  return __builtin_amdgcn_rcpf(1.f + __expf(-x));
}
__device__ __forceinline__ float fast_tanh(float x) {
  x = fminf(15.f, fmaxf(-15.f, x));
  float e = __expf(2.f * x);
  return 1.f - 2.f * __builtin_amdgcn_rcpf(e + 1.f);
}

// ---------------------------------------------------------------------------
// Kernel 1: LSTM cell.
// grid = (128, 4): blockIdx.x -> 128-sample block, blockIdx.y -> 64 h-units.
// block = 256 threads (4 waves); wave: 32 samples x (64 h x 4 gates).
// ---------------------------------------------------------------------------
__global__ __launch_bounds__(256) void lstm_kernel(
    const float* __restrict__ x, const float* __restrict__ hp,
    const float* __restrict__ cp,
    const float* __restrict__ Wih, const float* __restrict__ Whh,
    const float* __restrict__ bih, const float* __restrict__ bhh,
    float* __restrict__ out) {
  const int lane = threadIdx.x & 63;
  const int wv = threadIdx.x >> 6;
  const int s = lane & 15, q = lane >> 4;
  const int sb = blockIdx.x * 128 + wv * 32;   // wave sample base
  const int hb = blockIdx.y * 64;              // h-unit base

  f32x4 acc[2][16];   // [m-tile][gate*4 + ntl]
#pragma unroll
  for (int mt = 0; mt < 2; ++mt)
#pragma unroll
    for (int tn = 0; tn < 16; ++tn) acc[mt][tn] = (f32x4){0.f, 0.f, 0.f, 0.f};

  float bsum[16];
#pragma unroll
  for (int tn = 0; tn < 16; ++tn) {
    int n = (tn >> 2) * 256 + hb + (tn & 3) * 16 + s;
    bsum[tn] = bih[n] + bhh[n];
  }

  // K = 512: k<256 from input@W_ih, k>=256 from h_prev@W_hh
  for (int kk = 0; kk < 16; ++kk) {
    const int k0 = kk * 32;
    const float* asrc = (k0 < 256) ? x : hp;
    const float* wsrc = (k0 < 256) ? Wih : Whh;
    const int kl = k0 & 255;
    short8 af[2];
#pragma unroll
    for (int mt = 0; mt < 2; ++mt)
      af[mt] = pack8(asrc + (size_t)(sb + mt * 16 + s) * 256 + kl + q * 8);
#pragma unroll
    for (int tn = 0; tn < 16; ++tn) {
      int n = (tn >> 2) * 256 + hb + (tn & 3) * 16 + s;
      short8 bf = pack8(wsrc + (size_t)n * 256 + kl + q * 8);
#pragma unroll
      for (int mt = 0; mt < 2; ++mt)
        acc[mt][tn] =
            __builtin_amdgcn_mfma_f32_16x16x32_bf16(af[mt], bf, acc[mt][tn], 0, 0, 0);
    }
  }

  // epilogue: gates -> (h, c)
#pragma unroll
  for (int mt = 0; mt < 2; ++mt)
#pragma unroll
    for (int ntl = 0; ntl < 4; ++ntl)
#pragma unroll
      for (int r = 0; r < 4; ++r) {
        int sample = sb + mt * 16 + q * 4 + r;
        int h = hb + ntl * 16 + s;
        float gi = acc[mt][ntl][r]      + bsum[ntl];
        float gf = acc[mt][4 + ntl][r]  + bsum[4 + ntl];
        float gg = acc[mt][8 + ntl][r]  + bsum[8 + ntl];
        float go = acc[mt][12 + ntl][r] + bsum[12 + ntl];
        float iv = fast_sigmoid(gi), fv = fast_sigmoid(gf);
        float gv = fast_tanh(gg), ov = fast_sigmoid(go);
        float c = fv * cp[(size_t)sample * 256 + h] + iv * gv;
        float hv = ov * fast_tanh(c);
        out[(size_t)B_N * H_N + (size_t)sample * 256 + h] = c;
        out[(size_t)sample * 256 + h] = hv;
      }
}

// ---------------------------------------------------------------------------
// Kernel 2: dopri5 ODE. 16 samples/block, 256 threads (4 waves).
// LDS state swizzled by row (16-byte-chunk XOR) to spread banks.
// ---------------------------------------------------------------------------
#define SWZF(row, off) (((row) << 10) + ((off) ^ (((row) & 7) << 4)))  // f32 [16][256]
#define SWZA(row, off) (((row) << 9) + ((off) ^ (((row) & 7) << 4)))   // bf16 [16][256]
#define SWZZ(row, off) (((row) << 7) + ((off) ^ (((row) & 7) << 4)))   // bf16 [16][64]

__global__ __launch_bounds__(256) void ode_kernel(
    float* __restrict__ out, const float* __restrict__ ts,
    const float* __restrict__ W1, const float* __restrict__ b1,
    const float* __restrict__ W2, const float* __restrict__ b2) {
  __shared__ __align__(16) float ybuf[16 * 256];
  __shared__ __align__(16) float kbuf[5 * 16 * 256];
  __shared__ __align__(16) float accbuf[16 * 256];
  __shared__ __align__(16) unsigned short argb[16 * 256];
  __shared__ __align__(16) unsigned short zbuf[16 * 64];
  char* yb = (char*)ybuf;
  char* kb = (char*)kbuf;
  char* ab = (char*)accbuf;
  char* gbuf = (char*)argb;
  char* zb = (char*)zbuf;

  const int tid = threadIdx.x;
  const int lane = tid & 63, wv = tid >> 6;
  const int s = lane & 15, q = lane >> 4;
  const int se = tid >> 4, ce = tid & 15;  // elementwise: sample, 16-elem chunk
  const int bb = blockIdx.x * 16;

  // --- preload weight B-frags (once; weights stay in VGPRs) ---
  short8 w1f[8];
#pragma unroll
  for (int kt = 0; kt < 8; ++kt)
    w1f[kt] = pack8(W1 + (size_t)(wv * 16 + s) * 256 + kt * 32 + q * 8);
  short8 w2f[4][2];
#pragma unroll
  for (int i = 0; i < 4; ++i)
#pragma unroll
    for (int kt = 0; kt < 2; ++kt)
      w2f[i][kt] = pack8(W2 + (size_t)((wv * 4 + i) * 16 + s) * 64 + kt * 32 + q * 8);
  const float b1v = b1[wv * 16 + s];
  float b2v[4];
#pragma unroll
  for (int i = 0; i < 4; ++i) b2v[i] = b2[(wv * 4 + i) * 16 + s];

  const float dtv = ts[bb + se] * 0.125f;

  // --- load y0 (written by lstm_kernel into out[0:B*H]) ---
#pragma unroll
  for (int j = 0; j < 4; ++j) {
    f32x4 v = *(const f32x4*)(out + (size_t)(bb + se) * 256 + ce * 16 + j * 4);
    *(f32x4*)(yb + SWZF(se, ce * 64 + j * 16)) = v;
  }
  __syncthreads();

  // one ode_f eval: argb(bf16) -> mm1 -> tanh -> zb(bf16) -> mm2 -> kbuf[dslot](f32)
  auto run_mm = [&](int dslot) {
    char* kd = kb + dslot * 16384;
    f32x4 acc1 = (f32x4){0.f, 0.f, 0.f, 0.f};
#pragma unroll
    for (int kt = 0; kt < 8; ++kt) {
      short8 a = *(const short8*)(gbuf + SWZA(s, kt * 64 + q * 16));
      acc1 = __builtin_amdgcn_mfma_f32_16x16x32_bf16(a, w1f[kt], acc1, 0, 0, 0);
    }
#pragma unroll
    for (int r = 0; r < 4; ++r) {
      int m = q * 4 + r;  // sample row
      float z = fast_tanh(acc1[r] + b1v);
      *(unsigned short*)(zb + SWZZ(m, 2 * (wv * 16 + s))) = f2bf(z);
    }
    __syncthreads();
    short8 za[2];
#pragma unroll
    for (int kt = 0; kt < 2; ++kt)
      za[kt] = *(const short8*)(zb + SWZZ(s, kt * 64 + q * 16));
#pragma unroll
    for (int i = 0; i < 4; ++i) {
      f32x4 a2 = (f32x4){0.f, 0.f, 0.f, 0.f};
#pragma unroll
      for (int kt = 0; kt < 2; ++kt)
        a2 = __builtin_amdgcn_mfma_f32_16x16x32_bf16(za[kt], w2f[i][kt], a2, 0, 0, 0);
#pragma unroll
      for (int r = 0; r < 4; ++r) {
        int m = q * 4 + r;
        int n = (wv * 4 + i) * 16 + s;
        *(float*)(kd + SWZF(m, n * 4)) = a2[r] + b2v[i];
      }
    }
  };

#define YL(j) (*(const f32x4*)(yb + SWZF(se, ce * 64 + (j) * 16)))
#define KL(sl, j) (*(const f32x4*)(kb + (sl) * 16384 + SWZF(se, ce * 64 + (j) * 16)))
#define ACCL(j) (*(const f32x4*)(ab + SWZF(se, ce * 64 + (j) * 16)))
#define ST_ARG(j, v)                                              \
  do {                                                            \
    short4v t_;                                                   \
    t_[0] = (short)f2bf((v)[0]); t_[1] = (short)f2bf((v)[1]);     \
    t_[2] = (short)f2bf((v)[2]); t_[3] = (short)f2bf((v)[3]);     \
    *(short4v*)(gbuf + SWZA(se, ce * 32 + (j) * 8)) = t_;         \
  } while (0)

  const float A21 = 0.2f;
  const float A31 = 3.f / 40.f, A32 = 9.f / 40.f;
  const float A41 = 44.f / 45.f, A42 = -56.f / 15.f, A43 = 32.f / 9.f;
  const float A51 = 19372.f / 6561.f, A52 = -25360.f / 2187.f,
              A53 = 64448.f / 6561.f, A54 = -212.f / 729.f;
  const float A61 = 9017.f / 3168.f, A62 = -355.f / 33.f, A63 = 46732.f / 5247.f,
              A64 = 49.f / 176.f, A65 = -5103.f / 18656.f;
  const float C1 = 35.f / 384.f, C3 = 500.f / 1113.f, C4 = 125.f / 192.f,
              C5 = -2187.f / 6784.f, C6 = 11.f / 84.f;

  for (int st = 0; st < 8; ++st) {
    // stage 1: arg = y
#pragma unroll
    for (int j = 0; j < 4; ++j) { f32x4 a = YL(j); ST_ARG(j, a); }
    __syncthreads();
    run_mm(0);  // k1
    __syncthreads();
    // stage 2
#pragma unroll
    for (int j = 0; j < 4; ++j) {
      f32x4 a = YL(j) + dtv * (A21 * KL(0, j));
      ST_ARG(j, a);
    }
    __syncthreads();
    run_mm(1);  // k2
    __syncthreads();
    // stage 3
#pragma unroll
    for (int j = 0; j < 4; ++j) {
      f32x4 a = YL(j) + dtv * (A31 * KL(0, j) + A32 * KL(1, j));
      ST_ARG(j, a);
    }
    __syncthreads();
    run_mm(2);  // k3
    __syncthreads();
    // stage 4
#pragma unroll
    for (int j = 0; j < 4; ++j) {
      f32x4 a = YL(j) + dtv * (A41 * KL(0, j) + A42 * KL(1, j) + A43 * KL(2, j));
      ST_ARG(j, a);
    }
    __syncthreads();
    run_mm(3);  // k4
    __syncthreads();
    // stage 5
#pragma unroll
    for (int j = 0; j < 4; ++j) {
      f32x4 a = YL(j) + dtv * (A51 * KL(0, j) + A52 * KL(1, j) + A53 * KL(2, j) +
                               A54 * KL(3, j));
      ST_ARG(j, a);
    }
    __syncthreads();
    run_mm(4);  // k5
    __syncthreads();
    // stage 6 arg + fold y_next partial (frees k1..k5; k2 unused in y_next)
#pragma unroll
    for (int j = 0; j < 4; ++j) {
      const int co = ce * 64 + j * 16;
      f32x4 y = YL(j);
      f32x4 k1 = KL(0, j), k2 = KL(1, j), k3 = KL(2, j), k4 = KL(3, j), k5 = KL(4, j);
      f32x4 arg = y + dtv * (A61 * k1 + A62 * k2 + A63 * k3 + A64 * k4 + A65 * k5);
      f32x4 acc = y + dtv * (C1 * k1 + C3 * k3 + C4 * k4 + C5 * k5);
      *(f32x4*)(ab + SWZF(se, co)) = acc;
      ST_ARG(j, arg);
    }
    __syncthreads();
    run_mm(0);  // k6 -> slot 0
    __syncthreads();
    // y = acc + dt*C6*k6
#pragma unroll
    for (int j = 0; j < 4; ++j) {
      const int co = ce * 64 + j * 16;
      f32x4 a = ACCL(j) + (dtv * C6) * KL(0, j);
      *(f32x4*)(yb + SWZF(se, co)) = a;
    }
    __syncthreads();
  }

  // store h_ode
#pragma unroll
  for (int j = 0; j < 4; ++j) {
    f32x4 v = YL(j);
    *(f32x4*)(out + (size_t)(bb + se) * 256 + ce * 16 + j * 4) = v;
  }
}

extern "C" void kernel_launch(void* const* d_in, const int* in_sizes, int n_in,
                              void* d_out, int out_size, void* d_ws, size_t ws_size,
                              hipStream_t stream) {
  const float* x   = (const float*)d_in[0];
  const float* hp  = (const float*)d_in[1];
  const float* cp  = (const float*)d_in[2];
  const float* ts  = (const float*)d_in[3];
  const float* Wih = (const float*)d_in[4];
  const float* Whh = (const float*)d_in[5];
  const float* bih = (const float*)d_in[6];
  const float* bhh = (const float*)d_in[7];
  const float* W1  = (const float*)d_in[8];
  const float* b1  = (const float*)d_in[9];
  const float* W2  = (const float*)d_in[10];
  const float* b2  = (const float*)d_in[11];
  float* out = (float*)d_out;

  dim3 g1(128, 4);
  lstm_kernel<<<g1, 256, 0, stream>>>(x, hp, cp, Wih, Whh, bih, bhh, out);
  ode_kernel<<<1024, 256, 0, stream>>>(out, ts, W1, b1, W2, b2);
}

// Round 2
// 147.647 us; speedup vs baseline: 3.1491x; 3.1491x over previous
//
#include <hip/hip_runtime.h>
#include <hip/hip_bf16.h>

// ODELSTMCell: B=16384, I=256, H=256, OH=64, 8 fixed dopri5 steps.
// prep_kernel : W_ih|W_hh -> bf16 [1024][512] in d_ws (gate-stacked rows).
// lstm_kernel : MFMA GEMM, LDS-staged via global_load_lds(16B), fused epilogue.
//               writes h(=y0) -> out[0:BH), c -> out[BH:2BH).
// ode_kernel  : dopri5; k1..k5/y/acc in registers (MFMA C/D layout);
//               LDS only for arg (A-frag exchange, swizzled) + z.

#define B_N 16384
#define H_N 256

typedef __attribute__((ext_vector_type(8))) short short8;   // 8 x bf16
typedef __attribute__((ext_vector_type(4))) float f32x4;

__device__ __forceinline__ unsigned short f2bf_s(float x) {
  __hip_bfloat16 h = __float2bfloat16(x);   // RNE; compiler emits v_cvt_pk pairs
  return *reinterpret_cast<unsigned short*>(&h);
}

__device__ __forceinline__ short8 pack8f(const float* p) {
  const f32x4 a = *(const f32x4*)p;
  const f32x4 b = *(const f32x4*)(p + 4);
  short8 r;
  r[0] = (short)f2bf_s(a[0]); r[1] = (short)f2bf_s(a[1]);
  r[2] = (short)f2bf_s(a[2]); r[3] = (short)f2bf_s(a[3]);
  r[4] = (short)f2bf_s(b[0]); r[5] = (short)f2bf_s(b[1]);
  r[6] = (short)f2bf_s(b[2]); r[7] = (short)f2bf_s(b[3]);
  return r;
}

__device__ __forceinline__ float fast_sigmoid(float x) {
  return __builtin_amdgcn_rcpf(1.f + __expf(-x));
}
__device__ __forceinline__ float fast_tanh(float x) {
  x = fminf(15.f, fmaxf(-15.f, x));
  float e = __expf(2.f * x);
  return 1.f - 2.f * __builtin_amdgcn_rcpf(e + 1.f);
}

__device__ __forceinline__ void gl_lds16(const void* g, void* l) {
  __builtin_amdgcn_global_load_lds(
      (const __attribute__((address_space(1))) void*)g,
      (__attribute__((address_space(3))) void*)l, 16, 0, 0);
}

// ---------------------------------------------------------------------------
// prep: ws_B[1024][512] bf16; row n: k<256 from W_ih[n], k>=256 from W_hh[n].
// ---------------------------------------------------------------------------
__global__ __launch_bounds__(256) void prep_kernel(
    const float* __restrict__ Wih, const float* __restrict__ Whh,
    unsigned short* __restrict__ wsB) {
  int idx = blockIdx.x * 256 + threadIdx.x;   // 65536 threads, 8 elems each
  int n = idx >> 6, c = idx & 63, k = c * 8;
  const float* src = (k < 256) ? (Wih + (size_t)n * 256 + k)
                               : (Whh + (size_t)n * 256 + (k - 256));
  *(short8*)(wsB + (size_t)n * 512 + k) = pack8f(src);
}

// ---------------------------------------------------------------------------
// lstm: grid (128, 4), 256 thr. Block: 128 samples x (64 h x 4 gates).
// LDS: As f32 [128][64] (chunk-swizzled ^row&15), Bs bf16 [256][64] (^row&7).
// ---------------------------------------------------------------------------
__global__ __launch_bounds__(256, 2) void lstm_kernel(
    const float* __restrict__ x, const float* __restrict__ hp,
    const float* __restrict__ cp, const unsigned short* __restrict__ wsB,
    const float* __restrict__ bih, const float* __restrict__ bhh,
    float* __restrict__ out) {
  __shared__ __align__(16) float As[128 * 64];
  __shared__ __align__(16) unsigned short Bs[256 * 64];

  const int lane = threadIdx.x & 63;
  const int wv = threadIdx.x >> 6;
  const int s = lane & 15, q = lane >> 4;
  const int mb = blockIdx.x * 128;
  const int hb = blockIdx.y * 64;

  f32x4 acc[2][16];
#pragma unroll
  for (int mt = 0; mt < 2; ++mt)
#pragma unroll
    for (int tn = 0; tn < 16; ++tn) acc[mt][tn] = (f32x4){0.f, 0.f, 0.f, 0.f};

  float bsum[16];
#pragma unroll
  for (int tn = 0; tn < 16; ++tn) {
    int n = (tn >> 2) * 256 + hb + (tn & 3) * 16 + s;
    bsum[tn] = bih[n] + bhh[n];
  }

  for (int kt8 = 0; kt8 < 8; ++kt8) {
    const int k0 = kt8 * 64;
    if (kt8) __syncthreads();  // WAR: previous compute done
    // --- stage A (f32 [128][64], swizzle ch^(row&15)) ---
    {
      const float* srcA = (k0 < 256) ? x : hp;
      const int kl = k0 & 255;
#pragma unroll
      for (int c = 0; c < 8; ++c) {
        int row = (wv * 8 + c) * 4 + (lane >> 4);
        int cc = lane & 15;
        int uc = cc ^ (row & 15);
        gl_lds16(srcA + (size_t)(mb + row) * 256 + kl + uc * 4,
                 (char*)As + (wv * 8 + c) * 1024);
      }
    }
    // --- stage B (bf16 [256][64], swizzle ch^(row&7)) ---
#pragma unroll
    for (int c = 0; c < 8; ++c) {
      int t = (wv * 8 + c) * 8 + (lane >> 3);
      int cc = lane & 7;
      int uc = cc ^ (t & 7);
      int gr = (t >> 6) * 256 + hb + (t & 63);
      gl_lds16(wsB + (size_t)gr * 512 + k0 + uc * 8,
               (char*)Bs + (wv * 8 + c) * 1024);
    }
    __syncthreads();

    // --- compute: 2 x K=32 ---
#pragma unroll
    for (int kk = 0; kk < 2; ++kk) {
      short8 af[2];
#pragma unroll
      for (int mt = 0; mt < 2; ++mt) {
        int ar = wv * 32 + mt * 16 + s;
        int c0 = kk * 8 + q * 2;
        float tmp[8];
        *(f32x4*)tmp = *(const f32x4*)((char*)As + ar * 256 + ((c0 ^ (ar & 15)) * 16));
        *(f32x4*)(tmp + 4) =
            *(const f32x4*)((char*)As + ar * 256 + (((c0 + 1) ^ (ar & 15)) * 16));
        af[mt] = pack8f(tmp);
      }
#pragma unroll
      for (int tn = 0; tn < 16; ++tn) {
        int t = (tn >> 2) * 64 + (tn & 3) * 16 + s;
        int ch = (kk * 4 + q) ^ (t & 7);
        short8 bf = *(const short8*)((char*)Bs + t * 128 + ch * 16);
        acc[0][tn] = __builtin_amdgcn_mfma_f32_16x16x32_bf16(af[0], bf, acc[0][tn], 0, 0, 0);
        acc[1][tn] = __builtin_amdgcn_mfma_f32_16x16x32_bf16(af[1], bf, acc[1][tn], 0, 0, 0);
      }
    }
  }

  // --- fused epilogue ---
#pragma unroll
  for (int mt = 0; mt < 2; ++mt)
#pragma unroll
    for (int ntl = 0; ntl < 4; ++ntl)
#pragma unroll
      for (int r = 0; r < 4; ++r) {
        int sample = mb + wv * 32 + mt * 16 + q * 4 + r;
        int h = hb + ntl * 16 + s;
        float gi = acc[mt][ntl][r]      + bsum[ntl];
        float gf = acc[mt][4 + ntl][r]  + bsum[4 + ntl];
        float gg = acc[mt][8 + ntl][r]  + bsum[8 + ntl];
        float go = acc[mt][12 + ntl][r] + bsum[12 + ntl];
        float iv = fast_sigmoid(gi), fv = fast_sigmoid(gf);
        float gv = fast_tanh(gg), ov = fast_sigmoid(go);
        float c = fv * cp[(size_t)sample * 256 + h] + iv * gv;
        float hv = ov * fast_tanh(c);
        out[(size_t)B_N * H_N + (size_t)sample * 256 + h] = c;
        out[(size_t)sample * 256 + h] = hv;
      }
}

// ---------------------------------------------------------------------------
// ode: 16 samples/block, 256 thr (4 waves). k/y/acc in regs (MFMA layout:
// thread owns rows m=q*4+r, cols n=(wv*4+i)*16+s). LDS: arg 8KB + z 2KB.
// ---------------------------------------------------------------------------
__global__ __launch_bounds__(256, 2) void ode_kernel(
    float* __restrict__ out, const float* __restrict__ ts,
    const float* __restrict__ W1, const float* __restrict__ b1,
    const float* __restrict__ W2, const float* __restrict__ b2) {
  __shared__ __align__(16) unsigned short argL[16 * 256];  // bf16, swizzled
  __shared__ __align__(16) unsigned short zL[16 * 64];     // bf16, swizzled
  char* argB = (char*)argL;
  char* zB = (char*)zL;

  const int tid = threadIdx.x;
  const int lane = tid & 63, wv = tid >> 6;
  const int s = lane & 15, q = lane >> 4;
  const int bb = blockIdx.x * 16;

  // weight fragments (persistent registers)
  short8 w1f[8];
#pragma unroll
  for (int kt = 0; kt < 8; ++kt)
    w1f[kt] = pack8f(W1 + (size_t)(wv * 16 + s) * 256 + kt * 32 + q * 8);
  short8 w2f[4][2];
#pragma unroll
  for (int i = 0; i < 4; ++i)
#pragma unroll
    for (int kt = 0; kt < 2; ++kt)
      w2f[i][kt] = pack8f(W2 + (size_t)((wv * 4 + i) * 16 + s) * 64 + kt * 32 + q * 8);
  const float b1v = b1[wv * 16 + s];
  f32x4 b2v4[4];
#pragma unroll
  for (int i = 0; i < 4; ++i) {
    float v = b2[(wv * 4 + i) * 16 + s];
    b2v4[i] = (f32x4){v, v, v, v};
  }

  const f32x4 dt4 = 0.125f * (*(const f32x4*)(ts + bb + q * 4));

  // y0: out[0:BH) from lstm
  f32x4 yreg[4];
#pragma unroll
  for (int i = 0; i < 4; ++i)
#pragma unroll
    for (int r = 0; r < 4; ++r)
      yreg[i][r] = out[(size_t)(bb + q * 4 + r) * 256 + (wv * 4 + i) * 16 + s];

  f32x4 k1[4], k2[4], k3[4], k4[4], k5[4], argv[4], accv[4];

// one ode_f eval: argv (regs) -> arg LDS bf16 -> mm1 -> tanh -> z LDS -> mm2
#define EVAL(KOUT)                                                            \
  do {                                                                        \
    _Pragma("unroll") for (int i = 0; i < 4; ++i) {                           \
      int n = (wv * 4 + i) * 16 + s;                                          \
      _Pragma("unroll") for (int r = 0; r < 4; ++r) {                         \
        int m = q * 4 + r;                                                    \
        *(unsigned short*)(argB + m * 512 + ((((n >> 3) ^ (m & 7)) << 4) +    \
                                             (n & 7) * 2)) =                  \
            f2bf_s(argv[i][r]);                                               \
      }                                                                       \
    }                                                                         \
    __syncthreads();                                                          \
    f32x4 acc1 = (f32x4){0.f, 0.f, 0.f, 0.f};                                 \
    _Pragma("unroll") for (int kt = 0; kt < 8; ++kt) {                        \
      short8 a = *(const short8*)(argB + s * 512 +                            \
                                  (((kt * 4 + q) ^ (s & 7)) << 4));           \
      acc1 = __builtin_amdgcn_mfma_f32_16x16x32_bf16(a, w1f[kt], acc1, 0, 0, 0); \
    }                                                                         \
    _Pragma("unroll") for (int r = 0; r < 4; ++r) {                           \
      int m = q * 4 + r;                                                      \
      int n1 = wv * 16 + s;                                                   \
      float z = fast_tanh(acc1[r] + b1v);                                     \
      *(unsigned short*)(zB + m * 128 + ((((n1 >> 3) ^ (m & 7)) << 4) +       \
                                         (n1 & 7) * 2)) = f2bf_s(z);          \
    }                                                                         \
    __syncthreads();                                                          \
    short8 za0 = *(const short8*)(zB + s * 128 + ((q ^ (s & 7)) << 4));       \
    short8 za1 = *(const short8*)(zB + s * 128 + (((4 + q) ^ (s & 7)) << 4)); \
    _Pragma("unroll") for (int i = 0; i < 4; ++i) {                           \
      f32x4 a2 = (f32x4){0.f, 0.f, 0.f, 0.f};                                 \
      a2 = __builtin_amdgcn_mfma_f32_16x16x32_bf16(za0, w2f[i][0], a2, 0, 0, 0); \
      a2 = __builtin_amdgcn_mfma_f32_16x16x32_bf16(za1, w2f[i][1], a2, 0, 0, 0); \
      KOUT[i] = a2 + b2v4[i];                                                 \
    }                                                                         \
  } while (0)

  const float A21 = 0.2f;
  const float A31 = 3.f / 40.f, A32 = 9.f / 40.f;
  const float A41 = 44.f / 45.f, A42 = -56.f / 15.f, A43 = 32.f / 9.f;
  const float A51 = 19372.f / 6561.f, A52 = -25360.f / 2187.f,
              A53 = 64448.f / 6561.f, A54 = -212.f / 729.f;
  const float A61 = 9017.f / 3168.f, A62 = -355.f / 33.f, A63 = 46732.f / 5247.f,
              A64 = 49.f / 176.f, A65 = -5103.f / 18656.f;
  const float C1 = 35.f / 384.f, C3 = 500.f / 1113.f, C4 = 125.f / 192.f,
              C5 = -2187.f / 6784.f, C6 = 11.f / 84.f;

  for (int st = 0; st < 8; ++st) {
#pragma unroll
    for (int i = 0; i < 4; ++i) argv[i] = yreg[i];
    EVAL(k1);
#pragma unroll
    for (int i = 0; i < 4; ++i) argv[i] = yreg[i] + dt4 * (A21 * k1[i]);
    EVAL(k2);
#pragma unroll
    for (int i = 0; i < 4; ++i)
      argv[i] = yreg[i] + dt4 * (A31 * k1[i] + A32 * k2[i]);
    EVAL(k3);
#pragma unroll
    for (int i = 0; i < 4; ++i)
      argv[i] = yreg[i] + dt4 * (A41 * k1[i] + A42 * k2[i] + A43 * k3[i]);
    EVAL(k4);
#pragma unroll
    for (int i = 0; i < 4; ++i)
      argv[i] = yreg[i] + dt4 * (A51 * k1[i] + A52 * k2[i] + A53 * k3[i] +
                                 A54 * k4[i]);
    EVAL(k5);
#pragma unroll
    for (int i = 0; i < 4; ++i) {
      argv[i] = yreg[i] + dt4 * (A61 * k1[i] + A62 * k2[i] + A63 * k3[i] +
                                 A64 * k4[i] + A65 * k5[i]);
      accv[i] = yreg[i] + dt4 * (C1 * k1[i] + C3 * k3[i] + C4 * k4[i] +
                                 C5 * k5[i]);
    }
    EVAL(k1);  // k6 -> k1 (dead)
#pragma unroll
    for (int i = 0; i < 4; ++i) yreg[i] = accv[i] + dt4 * (C6 * k1[i]);
  }

  // store h_ode
#pragma unroll
  for (int i = 0; i < 4; ++i)
#pragma unroll
    for (int r = 0; r < 4; ++r)
      out[(size_t)(bb + q * 4 + r) * 256 + (wv * 4 + i) * 16 + s] = yreg[i][r];
}

extern "C" void kernel_launch(void* const* d_in, const int* in_sizes, int n_in,
                              void* d_out, int out_size, void* d_ws, size_t ws_size,
                              hipStream_t stream) {
  const float* x   = (const float*)d_in[0];
  const float* hp  = (const float*)d_in[1];
  const float* cp  = (const float*)d_in[2];
  const float* ts  = (const float*)d_in[3];
  const float* Wih = (const float*)d_in[4];
  const float* Whh = (const float*)d_in[5];
  const float* bih = (const float*)d_in[6];
  const float* bhh = (const float*)d_in[7];
  const float* W1  = (const float*)d_in[8];
  const float* b1  = (const float*)d_in[9];
  const float* W2  = (const float*)d_in[10];
  const float* b2  = (const float*)d_in[11];
  float* out = (float*)d_out;
  unsigned short* wsB = (unsigned short*)d_ws;  // 1 MB bf16 weights

  prep_kernel<<<256, 256, 0, stream>>>(Wih, Whh, wsB);
  lstm_kernel<<<dim3(128, 4), 256, 0, stream>>>(x, hp, cp, wsB, bih, bhh, out);
  ode_kernel<<<1024, 256, 0, stream>>>(out, ts, W1, b1, W2, b2);
}